// Round 1
// baseline (1070.461 us; speedup 1.0000x reference)
//
#include <hip/hip_runtime.h>
#include <cstddef>
#include <cstdint>

#define BB 2
#define TT 2048
#define CC 2048
#define HH 16
#define DD 128
#define KVL 1024
#define KVPE 256
#define KVCON 768
#define BT (BB*TT)
#define EPSV 1.1920929e-07f
#define QSCALE 0.08838834764831845f   // 1/sqrt(128)

typedef short bfv8 __attribute__((ext_vector_type(8)));   // 8 bf16 (bit pattern)
typedef short bfv4 __attribute__((ext_vector_type(4)));
typedef float f32x4 __attribute__((ext_vector_type(4)));

__device__ __forceinline__ short f2bf(float f) {
    unsigned u = __builtin_bit_cast(unsigned, f);
    u += 0x7FFFu + ((u >> 16) & 1u);          // RNE
    return (short)(u >> 16);
}
__device__ __forceinline__ bfv8 pack8(const float4 a, const float4 b) {
    bfv8 r;
    r[0]=f2bf(a.x); r[1]=f2bf(a.y); r[2]=f2bf(a.z); r[3]=f2bf(a.w);
    r[4]=f2bf(b.x); r[5]=f2bf(b.y); r[6]=f2bf(b.z); r[7]=f2bf(b.w);
    return r;
}

// ---------------------------------------------------------------------------
// Generic f32-in/f32-out GEMM via bf16 MFMA. C = A(MxK) * B(KxN).
// Tile 64x64, BK=32, 256 threads (4 waves, 2x2), each wave 32x32.
// Grid: (N/64, M/64). All dims divisible.
// ---------------------------------------------------------------------------
__global__ __launch_bounds__(256) void gemm_kernel(
    const float* __restrict__ A, int lda,
    const float* __restrict__ B, int ldb,
    float* __restrict__ C, int ldc, int K)
{
    __shared__ short As[64][40];   // [m][k], stride 40 bf16 = 80B (16B aligned)
    __shared__ short Bt[64][40];   // [n][k] (B transposed)

    const int tid  = threadIdx.x;
    const int lane = tid & 63, wave = tid >> 6;
    const int lr = lane & 15, lg = lane >> 4;
    const int wr = wave >> 1, wc = wave & 1;
    const size_t bm = (size_t)blockIdx.y * 64, bn = (size_t)blockIdx.x * 64;

    f32x4 acc[2][2] = {};

    const int ar = tid >> 3, ac = (tid & 7) * 4;    // A loader: 32 rows/pass
    const int br = tid >> 4, bc = (tid & 15) * 4;   // B loader: 16 krows/pass

    for (int k0 = 0; k0 < K; k0 += 32) {
#pragma unroll
        for (int p = 0; p < 2; ++p) {
            float4 v = *(const float4*)&A[(bm + ar + p*32) * (size_t)lda + k0 + ac];
            bfv4 w; w[0]=f2bf(v.x); w[1]=f2bf(v.y); w[2]=f2bf(v.z); w[3]=f2bf(v.w);
            *(bfv4*)&As[ar + p*32][ac] = w;
        }
#pragma unroll
        for (int p = 0; p < 2; ++p) {
            int kk = br + p*16;
            float4 v = *(const float4*)&B[(size_t)(k0 + kk) * ldb + bn + bc];
            Bt[bc+0][kk] = f2bf(v.x);
            Bt[bc+1][kk] = f2bf(v.y);
            Bt[bc+2][kk] = f2bf(v.z);
            Bt[bc+3][kk] = f2bf(v.w);
        }
        __syncthreads();

        bfv8 a0 = *(const bfv8*)&As[wr*32 +      lr][lg*8];
        bfv8 a1 = *(const bfv8*)&As[wr*32 + 16 + lr][lg*8];
        bfv8 b0 = *(const bfv8*)&Bt[wc*32 +      lr][lg*8];
        bfv8 b1 = *(const bfv8*)&Bt[wc*32 + 16 + lr][lg*8];
        acc[0][0] = __builtin_amdgcn_mfma_f32_16x16x32_bf16(a0, b0, acc[0][0], 0, 0, 0);
        acc[0][1] = __builtin_amdgcn_mfma_f32_16x16x32_bf16(a0, b1, acc[0][1], 0, 0, 0);
        acc[1][0] = __builtin_amdgcn_mfma_f32_16x16x32_bf16(a1, b0, acc[1][0], 0, 0, 0);
        acc[1][1] = __builtin_amdgcn_mfma_f32_16x16x32_bf16(a1, b1, acc[1][1], 0, 0, 0);
        __syncthreads();
    }

#pragma unroll
    for (int i = 0; i < 2; ++i)
#pragma unroll
        for (int j = 0; j < 2; ++j)
#pragma unroll
            for (int r = 0; r < 4; ++r)
                C[(bm + wr*32 + i*16 + 4*lg + r) * (size_t)ldc + bn + wc*32 + j*16 + lr]
                    = acc[i][j][r];
}

// ---------------------------------------------------------------------------
// k = rmsnorm(k_content + rope(k_pe)) in-place; one wave per (b,t,h) row.
// ---------------------------------------------------------------------------
__global__ __launch_bounds__(256) void finalize_k(
    float* __restrict__ k, const float* __restrict__ kpe,
    const float* __restrict__ cosb, const float* __restrict__ sinb)
{
    const int row = blockIdx.x * 4 + (threadIdx.x >> 6);  // (b*T + t)*H + h
    const int l = threadIdx.x & 63;
    const int t = (row >> 4) & (TT - 1);
    const size_t base = (size_t)row * DD;

    float x1 = kpe[base + l], x2 = kpe[base + 64 + l];
    float c = cosb[t*64 + l], s = sinb[t*64 + l];
    float lo = k[base + l]      + x1*c + x2*s;
    float hi = k[base + 64 + l] - x1*s + x2*c;

    float ss = lo*lo + hi*hi;
#pragma unroll
    for (int o = 32; o; o >>= 1) ss += __shfl_xor(ss, o);
    float r = rsqrtf(ss * (1.0f/128.0f) + EPSV);
    k[base + l]      = lo * r;
    k[base + 64 + l] = hi * r;
}

// q = rmsnorm(q) * (1/sqrt(D)) in-place; one wave per row.
__global__ __launch_bounds__(256) void finalize_q(float* __restrict__ q)
{
    const int row = blockIdx.x * 4 + (threadIdx.x >> 6);
    const int l = threadIdx.x & 63;
    const size_t base = (size_t)row * DD;
    float a = q[base + 2*l], b = q[base + 2*l + 1];
    float ss = a*a + b*b;
#pragma unroll
    for (int o = 32; o; o >>= 1) ss += __shfl_xor(ss, o);
    float r = rsqrtf(ss * (1.0f/128.0f) + EPSV) * QSCALE;
    q[base + 2*l]     = a * r;
    q[base + 2*l + 1] = b * r;
}

// ---------------------------------------------------------------------------
// Flash attention (causal). Block = (b, h, 64-row q-tile), 4 waves, each wave
// owns 16 q rows. q already rmsnorm'd and scaled; k rmsnorm'd; v raw f32.
// Layouts (B,T,H,D). Output y (B,T,H,D) f32.
// ---------------------------------------------------------------------------
__global__ __launch_bounds__(256) void attn_kernel(
    const float* __restrict__ q, const float* __restrict__ k,
    const float* __restrict__ v, float* __restrict__ y)
{
    __shared__ short Ks[64][136];    // [key][d]   stride 272B (16B aligned)
    __shared__ short Vt[128][72];    // [d][key]   stride 144B (16B aligned)
    __shared__ short Ps[4][16][72];  // per-wave P tile [qrow][key]

    const int qt = blockIdx.x, h = blockIdx.y, b = blockIdx.z;
    const int tid = threadIdx.x;
    const int w = tid >> 6, lane = tid & 63;
    const int lr = lane & 15, lg = lane >> 4;

    // Q fragments for this wave's 16 rows (A-operand, 4 k-steps over D=128)
    bfv8 aq[4];
    {
        const int qrow = qt*64 + w*16 + lr;
        const size_t qb = (((size_t)b*TT + qrow)*HH + h) * DD;
#pragma unroll
        for (int ks = 0; ks < 4; ++ks) {
            const int d0 = ks*32 + lg*8;
            float4 f0 = *(const float4*)&q[qb + d0];
            float4 f1 = *(const float4*)&q[qb + d0 + 4];
            aq[ks] = pack8(f0, f1);
        }
    }

    f32x4 o[8] = {};
    float m[4]    = {-__builtin_inff(), -__builtin_inff(), -__builtin_inff(), -__builtin_inff()};
    float lsum[4] = {0.f, 0.f, 0.f, 0.f};

    const int skey = tid >> 2, sd0 = (tid & 3) * 32;

    for (int kt = 0; kt <= qt; ++kt) {
        // ---- stage K tile (row-major bf16) and V tile (transposed bf16) ----
        {
            const size_t kb = (((size_t)b*TT + kt*64 + skey)*HH + h) * DD + sd0;
#pragma unroll
            for (int jj = 0; jj < 4; ++jj) {
                float4 f0 = *(const float4*)&k[kb + jj*8];
                float4 f1 = *(const float4*)&k[kb + jj*8 + 4];
                *(bfv8*)&Ks[skey][sd0 + jj*8] = pack8(f0, f1);
            }
#pragma unroll
            for (int jj = 0; jj < 4; ++jj) {
                float4 f0 = *(const float4*)&v[kb + jj*8];
                float4 f1 = *(const float4*)&v[kb + jj*8 + 4];
                Vt[sd0+jj*8+0][skey] = f2bf(f0.x);
                Vt[sd0+jj*8+1][skey] = f2bf(f0.y);
                Vt[sd0+jj*8+2][skey] = f2bf(f0.z);
                Vt[sd0+jj*8+3][skey] = f2bf(f0.w);
                Vt[sd0+jj*8+4][skey] = f2bf(f1.x);
                Vt[sd0+jj*8+5][skey] = f2bf(f1.y);
                Vt[sd0+jj*8+6][skey] = f2bf(f1.z);
                Vt[sd0+jj*8+7][skey] = f2bf(f1.w);
            }
        }
        __syncthreads();

        // ---- S = Q K^T (16 x 64 per wave) ----
        f32x4 s[4];
#pragma unroll
        for (int ct = 0; ct < 4; ++ct) {
            f32x4 acc = {0.f, 0.f, 0.f, 0.f};
#pragma unroll
            for (int ks = 0; ks < 4; ++ks) {
                bfv8 bk = *(const bfv8*)&Ks[ct*16 + lr][ks*32 + lg*8];
                acc = __builtin_amdgcn_mfma_f32_16x16x32_bf16(aq[ks], bk, acc, 0, 0, 0);
            }
            s[ct] = acc;
        }

        const int rowg = qt*64 + w*16 + 4*lg;
        if (kt == qt) {   // diagonal tile: causal mask
#pragma unroll
            for (int ct = 0; ct < 4; ++ct)
#pragma unroll
                for (int r = 0; r < 4; ++r)
                    if (kt*64 + ct*16 + lr > rowg + r) s[ct][r] = -__builtin_inff();
        }

        // ---- online softmax ----
        float mt[4] = {-__builtin_inff(), -__builtin_inff(), -__builtin_inff(), -__builtin_inff()};
#pragma unroll
        for (int ct = 0; ct < 4; ++ct)
#pragma unroll
            for (int r = 0; r < 4; ++r) mt[r] = fmaxf(mt[r], s[ct][r]);
#pragma unroll
        for (int off = 1; off < 16; off <<= 1)
#pragma unroll
            for (int r = 0; r < 4; ++r) mt[r] = fmaxf(mt[r], __shfl_xor(mt[r], off));

        float alpha[4];
#pragma unroll
        for (int r = 0; r < 4; ++r) {
            float mn = fmaxf(m[r], mt[r]);
            alpha[r] = expf(m[r] - mn);   // m=-inf, mn finite -> 0
            m[r] = mn;
        }
#pragma unroll
        for (int ct = 0; ct < 4; ++ct)
#pragma unroll
            for (int r = 0; r < 4; ++r) s[ct][r] = expf(s[ct][r] - m[r]);

        float rs[4];
#pragma unroll
        for (int r = 0; r < 4; ++r) rs[r] = s[0][r] + s[1][r] + s[2][r] + s[3][r];
#pragma unroll
        for (int off = 1; off < 16; off <<= 1)
#pragma unroll
            for (int r = 0; r < 4; ++r) rs[r] += __shfl_xor(rs[r], off);
#pragma unroll
        for (int r = 0; r < 4; ++r) lsum[r] = lsum[r] * alpha[r] + rs[r];
#pragma unroll
        for (int dt = 0; dt < 8; ++dt) {
            o[dt][0] *= alpha[0]; o[dt][1] *= alpha[1];
            o[dt][2] *= alpha[2]; o[dt][3] *= alpha[3];
        }

        // ---- P -> LDS (C-layout -> A-layout transpose) ----
#pragma unroll
        for (int ct = 0; ct < 4; ++ct)
#pragma unroll
            for (int r = 0; r < 4; ++r)
                Ps[w][4*lg + r][ct*16 + lr] = f2bf(s[ct][r]);
        __syncthreads();

        // ---- O += P V ----
        bfv8 pa0 = *(const bfv8*)&Ps[w][lr][lg*8];
        bfv8 pa1 = *(const bfv8*)&Ps[w][lr][32 + lg*8];
#pragma unroll
        for (int dt = 0; dt < 8; ++dt) {
            bfv8 bv0 = *(const bfv8*)&Vt[dt*16 + lr][lg*8];
            bfv8 bv1 = *(const bfv8*)&Vt[dt*16 + lr][32 + lg*8];
            o[dt] = __builtin_amdgcn_mfma_f32_16x16x32_bf16(pa0, bv0, o[dt], 0, 0, 0);
            o[dt] = __builtin_amdgcn_mfma_f32_16x16x32_bf16(pa1, bv1, o[dt], 0, 0, 0);
        }
        __syncthreads();
    }

    const int rowg = qt*64 + w*16 + 4*lg;
#pragma unroll
    for (int r = 0; r < 4; ++r) {
        float inv = 1.0f / lsum[r];
        const size_t yb = (((size_t)b*TT + rowg + r)*HH + h) * DD;
#pragma unroll
        for (int dt = 0; dt < 8; ++dt)
            y[yb + dt*16 + lr] = o[dt][r] * inv;
    }
}

// ---------------------------------------------------------------------------
extern "C" void kernel_launch(void* const* d_in, const int* in_sizes, int n_in,
                              void* d_out, int out_size, void* d_ws, size_t ws_size,
                              hipStream_t stream)
{
    const float* x      = (const float*)d_in[0];
    const float* cosb   = (const float*)d_in[1];
    const float* sinb   = (const float*)d_in[2];
    const float* wq_a   = (const float*)d_in[3];
    const float* wq_b   = (const float*)d_in[4];
    const float* wkv_a  = (const float*)d_in[5];
    const float* wk_b   = (const float*)d_in[6];
    const float* wkpe_b = (const float*)d_in[7];
    const float* wv_b   = (const float*)d_in[8];
    const float* wo     = (const float*)d_in[9];
    float* out = (float*)d_out;

    float* ws = (float*)d_ws;
    const size_t M1 = 1048576;
    float* kvlat = ws;            //  4M floats
    float* kbuf  = ws + 4*M1;     //  8M
    float* kpe   = ws + 12*M1;    //  8M (reused later as qlat and ybuf)
    float* vbuf  = ws + 20*M1;    //  8M
    float* qbuf  = ws + 28*M1;    //  8M   total 36M floats = 144MB

    dim3 blk(256);

    // kv_latent = x @ wkv_a
    gemm_kernel<<<dim3(KVL/64, BT/64), blk, 0, stream>>>(x, CC, wkv_a, KVL, kvlat, KVL, CC);
    // k_content = kv_content @ wk_b
    gemm_kernel<<<dim3(CC/64, BT/64), blk, 0, stream>>>(kvlat + KVPE, KVL, wk_b, CC, kbuf, CC, KVCON);
    // k_pe = kv_pe @ wkpe_b
    gemm_kernel<<<dim3(CC/64, BT/64), blk, 0, stream>>>(kvlat, KVL, wkpe_b, CC, kpe, CC, KVPE);
    // v = kv_content @ wv_b
    gemm_kernel<<<dim3(CC/64, BT/64), blk, 0, stream>>>(kvlat + KVPE, KVL, wv_b, CC, vbuf, CC, KVCON);
    // k = rmsnorm(k_content + rope(k_pe))
    finalize_k<<<BT*HH/4, blk, 0, stream>>>(kbuf, kpe, cosb, sinb);

    // q path (reuse kpe region for q_latent)
    float* qlat = kpe;
    gemm_kernel<<<dim3(KVL/64, BT/64), blk, 0, stream>>>(x, CC, wq_a, KVL, qlat, KVL, CC);
    gemm_kernel<<<dim3(CC/64, BT/64), blk, 0, stream>>>(qlat, KVL, wq_b, CC, qbuf, CC, KVL);
    finalize_q<<<BT*HH/4, blk, 0, stream>>>(qbuf);

    // attention (reuse kpe region for y)
    float* ybuf = kpe;
    attn_kernel<<<dim3(TT/64, HH, BB), blk, 0, stream>>>(qbuf, kbuf, vbuf, ybuf);

    // out = y @ wo
    gemm_kernel<<<dim3(CC/64, BT/64), blk, 0, stream>>>(ybuf, CC, wo, CC, out, CC, CC);
}

// Round 2
// 399.118 us; speedup vs baseline: 2.6821x; 2.6821x over previous
//
#include <hip/hip_runtime.h>
#include <cstddef>
#include <cstdint>

#define TT 2048
#define HH 16
#define EPSV 1.1920929e-07f
#define QSCALE 0.08838834764831845f   // 1/sqrt(128)

typedef short bfv8 __attribute__((ext_vector_type(8)));
typedef float f32x4 __attribute__((ext_vector_type(4)));

__device__ __forceinline__ short f2bf(float f) {
    unsigned u = __builtin_bit_cast(unsigned, f);
    u += 0x7FFFu + ((u >> 16) & 1u);          // RNE
    return (short)(u >> 16);
}
__device__ __forceinline__ float bf2f(short s) {
    unsigned u = ((unsigned)(unsigned short)s) << 16;
    return __builtin_bit_cast(float, u);
}
__device__ __forceinline__ bfv8 pack8(const float4 a, const float4 b) {
    bfv8 r;
    r[0]=f2bf(a.x); r[1]=f2bf(a.y); r[2]=f2bf(a.z); r[3]=f2bf(a.w);
    r[4]=f2bf(b.x); r[5]=f2bf(b.y); r[6]=f2bf(b.z); r[7]=f2bf(b.w);
    return r;
}
__device__ __forceinline__ void gload16(const void* g, void* l) {
    __builtin_amdgcn_global_load_lds(
        (const __attribute__((address_space(1))) unsigned int*)g,
        (__attribute__((address_space(3))) unsigned int*)l, 16, 0, 0);
}

// ---------------------------------------------------------------------------
// convert f32 -> bf16 (same layout), n8 = elements/8
// ---------------------------------------------------------------------------
__global__ __launch_bounds__(256) void convx(const float* __restrict__ src,
                                             short* __restrict__ dst, int n8)
{
    int i = blockIdx.x * blockDim.x + threadIdx.x;
    int stride = gridDim.x * blockDim.x;
    for (; i < n8; i += stride) {
        float4 a = ((const float4*)src)[2*i], b = ((const float4*)src)[2*i+1];
        ((bfv8*)dst)[i] = pack8(a, b);
    }
}

// ---------------------------------------------------------------------------
// transpose-convert: src f32 [R][C] -> dst bf16 [C][R]. Grid (C/64, R/64).
// ---------------------------------------------------------------------------
__global__ __launch_bounds__(256) void wtrans(const float* __restrict__ src,
                                              short* __restrict__ dst, int R, int C)
{
    __shared__ short tile[64][72];
    const int tid = threadIdx.x;
    const int r0 = blockIdx.y * 64, c0 = blockIdx.x * 64;
    {
        const int i = tid >> 2, c = (tid & 3) * 16;
        const float* sp = src + ((size_t)(r0 + i)) * C + c0 + c;
        float4 v0 = ((const float4*)sp)[0], v1 = ((const float4*)sp)[1];
        float4 v2 = ((const float4*)sp)[2], v3 = ((const float4*)sp)[3];
        *(bfv8*)&tile[i][c]     = pack8(v0, v1);
        *(bfv8*)&tile[i][c + 8] = pack8(v2, v3);
    }
    __syncthreads();
    {
        const int j = tid >> 2, rc = (tid & 3) * 16;
        bfv8 g0, g1;
#pragma unroll
        for (int jj = 0; jj < 8; ++jj) { g0[jj] = tile[rc + jj][j]; g1[jj] = tile[rc + 8 + jj][j]; }
        short* dp = dst + ((size_t)(c0 + j)) * R + r0 + rc;
        *(bfv8*)dp       = g0;
        *(bfv8*)(dp + 8) = g1;
    }
}

// ---------------------------------------------------------------------------
// m97-structure GEMM: C = A(MxK) * B^T(NxK input layout), bf16 in, 128x128 tile,
// BK=32, 256 thr (4 waves 2x2, each 64x64 = 4x4 frags). Grid (N/128, M/128).
// OUT_MODE: 0 = f32 row-major, 1 = bf16 row-major.
// ---------------------------------------------------------------------------
template<int OUT_MODE>
__global__ __launch_bounds__(256) void gemm_bf16(
    const short* __restrict__ A, int lda,
    const short* __restrict__ B, int ldb,
    void* __restrict__ Cptr, int ldc, int K)
{
    __shared__ short As[128 * 32];
    __shared__ short Bs[128 * 32];
    const int tid = threadIdx.x;
    const int w = tid >> 6, lane = tid & 63;
    const int lr = lane & 15, lg = lane >> 4;
    const int wr = w >> 1, wc = w & 1;
    const size_t bm = (size_t)blockIdx.y * 128, bn = (size_t)blockIdx.x * 128;

    f32x4 acc[4][4] = {};

    const int r0 = tid >> 2, ch = (tid & 3) * 8;
    const short* aB0 = A + (bm + r0) * (size_t)lda + ch;
    const short* aB1 = aB0 + 64 * (size_t)lda;
    const short* bB0 = B + (bn + r0) * (size_t)ldb + ch;
    const short* bB1 = bB0 + 64 * (size_t)ldb;
    short* ldsA = As + w * 512;
    short* ldsB = Bs + w * 512;

    for (int k0 = 0; k0 < K; k0 += 32) {
        gload16(aB0 + k0, ldsA);
        gload16(aB1 + k0, ldsA + 2048);
        gload16(bB0 + k0, ldsB);
        gload16(bB1 + k0, ldsB + 2048);
        __syncthreads();

        bfv8 af[4], bfr[4];
#pragma unroll
        for (int i = 0; i < 4; ++i) {
            af[i]  = *(const bfv8*)&As[(wr * 64 + i * 16 + lr) * 32 + lg * 8];
            bfr[i] = *(const bfv8*)&Bs[(wc * 64 + i * 16 + lr) * 32 + lg * 8];
        }
#pragma unroll
        for (int i = 0; i < 4; ++i)
#pragma unroll
            for (int j = 0; j < 4; ++j)
                acc[i][j] = __builtin_amdgcn_mfma_f32_16x16x32_bf16(af[i], bfr[j], acc[i][j], 0, 0, 0);
        __syncthreads();
    }

    const size_t crow = bm + wr * 64 + 4 * lg;
    const size_t ccol = bn + wc * 64 + lr;
#pragma unroll
    for (int i = 0; i < 4; ++i)
#pragma unroll
        for (int j = 0; j < 4; ++j)
#pragma unroll
            for (int r = 0; r < 4; ++r) {
                size_t off = (crow + i * 16 + r) * (size_t)ldc + ccol + j * 16;
                if (OUT_MODE == 0) ((float*)Cptr)[off] = acc[i][j][r];
                else               ((short*)Cptr)[off] = f2bf(acc[i][j][r]);
            }
}

// ---------------------------------------------------------------------------
// k = rmsnorm(k_content + rope(k_pe)); bf16 in, bf16 head-major out [b,h,t,d]
// ---------------------------------------------------------------------------
__global__ __launch_bounds__(256) void finalize_k(
    const short* __restrict__ kc,   // KV2 [4096][4096], k_content = cols 0..2047
    const short* __restrict__ pe,   // [4096][2048]
    const float* __restrict__ cosb, const float* __restrict__ sinb,
    short* __restrict__ kb)
{
    const int gw = blockIdx.x * 4 + (threadIdx.x >> 6);
    const int l = threadIdx.x & 63;
    const int r = gw >> 4, h = gw & 15;
    const int t = r & (TT - 1), b = r >> 11;
    const size_t kcb = (size_t)r * 4096 + h * 128;
    const size_t peb = (size_t)r * 2048 + h * 128;

    float x1 = bf2f(pe[peb + l]), x2 = bf2f(pe[peb + 64 + l]);
    float c = cosb[t * 64 + l], s = sinb[t * 64 + l];
    float lo = bf2f(kc[kcb + l])      + x1 * c + x2 * s;
    float hi = bf2f(kc[kcb + 64 + l]) - x1 * s + x2 * c;

    float ss = lo * lo + hi * hi;
#pragma unroll
    for (int o = 32; o; o >>= 1) ss += __shfl_xor(ss, o);
    float rr = rsqrtf(ss * (1.0f / 128.0f) + EPSV);
    const size_t ob = (((size_t)b * HH + h) * TT + t) * 128;
    kb[ob + l]      = f2bf(lo * rr);
    kb[ob + 64 + l] = f2bf(hi * rr);
}

// q = rmsnorm(q)/sqrt(D); bf16 in row-major, bf16 head-major out
__global__ __launch_bounds__(256) void finalize_q(
    const short* __restrict__ qi, short* __restrict__ qo)
{
    const int gw = blockIdx.x * 4 + (threadIdx.x >> 6);
    const int l = threadIdx.x & 63;
    const int r = gw >> 4, h = gw & 15;
    const int t = r & (TT - 1), b = r >> 11;
    const short* qp = qi + (size_t)r * 2048 + h * 128 + 2 * l;
    float a = bf2f(qp[0]), bq = bf2f(qp[1]);
    float ss = a * a + bq * bq;
#pragma unroll
    for (int o = 32; o; o >>= 1) ss += __shfl_xor(ss, o);
    float rr = rsqrtf(ss * (1.0f / 128.0f) + EPSV) * QSCALE;
    short* op = qo + (((size_t)b * HH + h) * TT + t) * 128 + 2 * l;
    op[0] = f2bf(a * rr);
    op[1] = f2bf(bq * rr);
}

// v: KV2 cols 2048..4095 -> vb [b,h,d,t] bf16. Grid (T/64, 2, 32)
__global__ __launch_bounds__(256) void vtrans(
    const short* __restrict__ src, short* __restrict__ dst)
{
    __shared__ short tile[64][72];
    const int tt = blockIdx.x, dt = blockIdx.y, bh = blockIdx.z;
    const int tid = threadIdx.x;
    {
        const int i = tid >> 2, c = (tid & 3) * 16;
        const size_t sb = ((size_t)((bh >> 4) * TT + tt * 64 + i)) * 4096 + 2048 + (bh & 15) * 128 + dt * 64 + c;
        *(bfv8*)&tile[i][c]     = *(const bfv8*)&src[sb];
        *(bfv8*)&tile[i][c + 8] = *(const bfv8*)&src[sb + 8];
    }
    __syncthreads();
    {
        const int j = tid >> 2, rc = (tid & 3) * 16;
        bfv8 g0, g1;
#pragma unroll
        for (int jj = 0; jj < 8; ++jj) { g0[jj] = tile[rc + jj][j]; g1[jj] = tile[rc + 8 + jj][j]; }
        const size_t db = (((size_t)bh) * 128 + dt * 64 + j) * TT + tt * 64 + rc;
        *(bfv8*)&dst[db]     = g0;
        *(bfv8*)&dst[db + 8] = g1;
    }
}

// ---------------------------------------------------------------------------
// Flash attention, pair-balanced. Block pi handles q-tiles {pi, 31-pi} (64 rows
// each), 4 waves x 16 rows. K/V staged once per kt, shared by both tiles.
// qg,kg: [b,h,t,d] bf16; vg: [b,h,d,t] bf16; y: [4096][2048] bf16 row-major.
// ---------------------------------------------------------------------------
__device__ __forceinline__ void attn_tile(
    const short* __restrict__ Ks, const short* __restrict__ Vs,
    short (&Psw)[16][72], const bfv8 aq[4], f32x4 o[8],
    float m[4], float l[4], int lr, int lg, int w, bool diag)
{
    f32x4 s[4];
#pragma unroll
    for (int ct = 0; ct < 4; ++ct) {
        f32x4 a = {0.f, 0.f, 0.f, 0.f};
        const int row = ct * 16 + lr;
#pragma unroll
        for (int ks = 0; ks < 4; ++ks) {
            const bfv8 bk = *(const bfv8*)&Ks[row * 128 + (((ks * 4 + lg) ^ (row & 7)) * 8)];
            a = __builtin_amdgcn_mfma_f32_16x16x32_bf16(aq[ks], bk, a, 0, 0, 0);
        }
        s[ct] = a;
    }
    if (diag) {
        const int rq = w * 16 + 4 * lg;
#pragma unroll
        for (int ct = 0; ct < 4; ++ct)
#pragma unroll
            for (int r = 0; r < 4; ++r)
                if (ct * 16 + lr > rq + r) s[ct][r] = -__builtin_inff();
    }
    float mt[4];
#pragma unroll
    for (int r = 0; r < 4; ++r) mt[r] = fmaxf(fmaxf(s[0][r], s[1][r]), fmaxf(s[2][r], s[3][r]));
#pragma unroll
    for (int off = 1; off < 16; off <<= 1)
#pragma unroll
        for (int r = 0; r < 4; ++r) mt[r] = fmaxf(mt[r], __shfl_xor(mt[r], off));
    float alpha[4];
#pragma unroll
    for (int r = 0; r < 4; ++r) {
        float mn = fmaxf(m[r], mt[r]);
        alpha[r] = __expf(m[r] - mn);
        m[r] = mn;
    }
#pragma unroll
    for (int ct = 0; ct < 4; ++ct)
#pragma unroll
        for (int r = 0; r < 4; ++r) s[ct][r] = __expf(s[ct][r] - m[r]);
    float rs[4];
#pragma unroll
    for (int r = 0; r < 4; ++r) rs[r] = (s[0][r] + s[1][r]) + (s[2][r] + s[3][r]);
#pragma unroll
    for (int off = 1; off < 16; off <<= 1)
#pragma unroll
        for (int r = 0; r < 4; ++r) rs[r] += __shfl_xor(rs[r], off);
#pragma unroll
    for (int r = 0; r < 4; ++r) l[r] = l[r] * alpha[r] + rs[r];
#pragma unroll
    for (int dt = 0; dt < 8; ++dt) {
        o[dt][0] *= alpha[0]; o[dt][1] *= alpha[1];
        o[dt][2] *= alpha[2]; o[dt][3] *= alpha[3];
    }
#pragma unroll
    for (int ct = 0; ct < 4; ++ct)
#pragma unroll
        for (int r = 0; r < 4; ++r)
            Psw[4 * lg + r][ct * 16 + lr] = f2bf(s[ct][r]);
    const bfv8 pa0 = *(const bfv8*)&Psw[lr][lg * 8];
    const bfv8 pa1 = *(const bfv8*)&Psw[lr][32 + lg * 8];
#pragma unroll
    for (int dt = 0; dt < 8; ++dt) {
        const int row = dt * 16 + lr;
        const bfv8 bv0 = *(const bfv8*)&Vs[row * 64 + ((lg ^ (row & 7)) * 8)];
        const bfv8 bv1 = *(const bfv8*)&Vs[row * 64 + (((4 + lg) ^ (row & 7)) * 8)];
        o[dt] = __builtin_amdgcn_mfma_f32_16x16x32_bf16(pa0, bv0, o[dt], 0, 0, 0);
        o[dt] = __builtin_amdgcn_mfma_f32_16x16x32_bf16(pa1, bv1, o[dt], 0, 0, 0);
    }
}

__global__ __launch_bounds__(256) void attn_kernel(
    const short* __restrict__ qg, const short* __restrict__ kg,
    const short* __restrict__ vg, short* __restrict__ y)
{
    __shared__ short Ks[64 * 128];
    __shared__ short Vs[128 * 64];
    __shared__ short Ps[4][16][72];

    const int pi = blockIdx.x, h = blockIdx.y, b = blockIdx.z;
    const int qt1 = pi, qt2 = 31 - pi;
    const int tid = threadIdx.x, w = tid >> 6, lane = tid & 63;
    const int lr = lane & 15, lg = lane >> 4;

    const size_t tok0 = ((size_t)b * HH + h) * TT;
    bfv8 aq1[4], aq2[4];
    {
        const size_t q1 = (tok0 + qt1 * 64 + w * 16 + lr) * 128;
        const size_t q2 = (tok0 + qt2 * 64 + w * 16 + lr) * 128;
#pragma unroll
        for (int ks = 0; ks < 4; ++ks) {
            aq1[ks] = *(const bfv8*)&qg[q1 + ks * 32 + lg * 8];
            aq2[ks] = *(const bfv8*)&qg[q2 + ks * 32 + lg * 8];
        }
    }
    f32x4 o1[8] = {}; f32x4 o2[8] = {};
    float m1[4], l1[4], m2[4], l2[4];
#pragma unroll
    for (int r = 0; r < 4; ++r) { m1[r] = m2[r] = -__builtin_inff(); l1[r] = l2[r] = 0.f; }

    const size_t vhead = ((size_t)b * HH + h) * (size_t)128 * TT;
    const int krow = tid >> 4, kub = tid & 15;
    const int vrow = tid >> 3, vub = tid & 7;
    short* ldsK = Ks + w * 512;
    short* ldsV = Vs + w * 512;

    for (int kt = 0; kt <= qt2; ++kt) {
        const size_t kbase = (tok0 + kt * 64) * 128;
#pragma unroll
        for (int p = 0; p < 4; ++p) {
            int row = p * 16 + krow;
            int u = kub ^ (row & 7);
            gload16(kg + kbase + row * 128 + u * 8, ldsK + p * 2048);
            int rv = p * 32 + vrow;
            int uv = vub ^ (rv & 7);
            gload16(vg + vhead + (size_t)rv * TT + kt * 64 + uv * 8, ldsV + p * 2048);
        }
        __syncthreads();

        attn_tile(Ks, Vs, Ps[w], aq2, o2, m2, l2, lr, lg, w, kt == qt2);
        if (kt <= qt1)
            attn_tile(Ks, Vs, Ps[w], aq1, o1, m1, l1, lr, lg, w, kt == qt1);
        __syncthreads();
    }

#pragma unroll
    for (int r = 0; r < 4; ++r) {
        float inv1 = 1.0f / l1[r], inv2 = 1.0f / l2[r];
        const size_t y1 = ((size_t)b * TT + qt1 * 64 + w * 16 + 4 * lg + r) * 2048 + h * 128 + lr;
        const size_t y2 = ((size_t)b * TT + qt2 * 64 + w * 16 + 4 * lg + r) * 2048 + h * 128 + lr;
#pragma unroll
        for (int dt = 0; dt < 8; ++dt) {
            y[y1 + dt * 16] = f2bf(o1[dt][r] * inv1);
            y[y2 + dt * 16] = f2bf(o2[dt][r] * inv2);
        }
    }
}

// ---------------------------------------------------------------------------
extern "C" void kernel_launch(void* const* d_in, const int* in_sizes, int n_in,
                              void* d_out, int out_size, void* d_ws, size_t ws_size,
                              hipStream_t stream)
{
    const float* x      = (const float*)d_in[0];
    const float* cosb   = (const float*)d_in[1];
    const float* sinb   = (const float*)d_in[2];
    const float* wq_a   = (const float*)d_in[3];
    const float* wq_b   = (const float*)d_in[4];
    const float* wkv_a  = (const float*)d_in[5];
    const float* wk_b   = (const float*)d_in[6];
    const float* wkpe_b = (const float*)d_in[7];
    const float* wv_b   = (const float*)d_in[8];
    const float* wo     = (const float*)d_in[9];

    short* wsp = (short*)d_ws;
    short* W1  = wsp;                 // [2048][2048]  [wq_a^T ; wkv_a^T]
    short* W2  = wsp + 4194304;       // [4096][768]   [wk_b^T ; wv_b^T]
    short* W3  = wsp + 7340032;       // [2048][256]   wkpe_b^T
    short* W4  = wsp + 7864320;       // [2048][1024]  wq_b^T
    short* W5  = wsp + 9961472;       // [2048][2048]  wo^T
    short* C1  = wsp + 14155776;      // [4096][2048]  qlat|kvlat; later y
    short* KV2 = wsp + 22544384;      // [4096][4096]  k_content|v; later qb
    short* KPE = wsp + 39321600;      // [4096][2048]  k_pe; later qbuf
    short* KB  = wsp + 47710208;      // [b,h,t,d]
    short* VB  = wsp + 56098816;      // [b,h,d,t]
    short* XB  = (short*)d_out;       // x as bf16 (d_out reused as scratch)

    dim3 blk(256);

    convx<<<2048, blk, 0, stream>>>(x, XB, 1048576);
    wtrans<<<dim3(16, 32), blk, 0, stream>>>(wq_a,   W1,                2048, 1024);
    wtrans<<<dim3(16, 32), blk, 0, stream>>>(wkv_a,  W1 + 1024 * 2048,  2048, 1024);
    wtrans<<<dim3(32, 12), blk, 0, stream>>>(wk_b,   W2,                 768, 2048);
    wtrans<<<dim3(32, 12), blk, 0, stream>>>(wv_b,   W2 + 2048 * 768,    768, 2048);
    wtrans<<<dim3(32,  4), blk, 0, stream>>>(wkpe_b, W3,                 256, 2048);
    wtrans<<<dim3(32, 16), blk, 0, stream>>>(wq_b,   W4,                1024, 2048);
    wtrans<<<dim3(32, 32), blk, 0, stream>>>(wo,     W5,                2048, 2048);

    // [qlat|kvlat] = x @ [wq_a|wkv_a]
    gemm_bf16<1><<<dim3(16, 32), blk, 0, stream>>>(XB, 2048, W1, 2048, C1, 2048, 2048);
    // [k_content|v] = kv_content @ [wk_b|wv_b]
    gemm_bf16<1><<<dim3(32, 32), blk, 0, stream>>>(C1 + 1280, 2048, W2, 768, KV2, 4096, 768);
    // k_pe = kv_pe @ wkpe_b
    gemm_bf16<1><<<dim3(16, 32), blk, 0, stream>>>(C1 + 1024, 2048, W3, 256, KPE, 2048, 256);

    finalize_k<<<16384, blk, 0, stream>>>(KV2, KPE, cosb, sinb, KB);
    vtrans<<<dim3(32, 2, 32), blk, 0, stream>>>(KV2, VB);

    // qbuf = qlat @ wq_b  (into KPE slot)
    gemm_bf16<1><<<dim3(16, 32), blk, 0, stream>>>(C1, 2048, W4, 1024, KPE, 2048, 1024);
    finalize_q<<<16384, blk, 0, stream>>>(KPE, KV2);   // qb into KV2 slot

    // attention: y into C1 slot
    attn_kernel<<<dim3(16, 16, 2), blk, 0, stream>>>(KV2, KB, VB, C1);

    // out = y @ wo
    gemm_bf16<0><<<dim3(16, 32), blk, 0, stream>>>(C1, 2048, W5, 2048, d_out, 2048, 2048);
}

// Round 3
// 374.948 us; speedup vs baseline: 2.8550x; 1.0645x over previous
//
#include <hip/hip_runtime.h>
#include <cstddef>
#include <cstdint>

#define TT 2048
#define HH 16
#define EPSV 1.1920929e-07f
#define QSCALE 0.08838834764831845f   // 1/sqrt(128)
#define LOG2E 1.4426950408889634f
#define THRL 11.0f                    // defer-rescale threshold (log2 units)

typedef short bfv8 __attribute__((ext_vector_type(8)));
typedef float f32x4 __attribute__((ext_vector_type(4)));

__device__ __forceinline__ short f2bf(float f) {
    unsigned u = __builtin_bit_cast(unsigned, f);
    u += 0x7FFFu + ((u >> 16) & 1u);          // RNE
    return (short)(u >> 16);
}
__device__ __forceinline__ float bf2f(short s) {
    unsigned u = ((unsigned)(unsigned short)s) << 16;
    return __builtin_bit_cast(float, u);
}
__device__ __forceinline__ bfv8 pack8(const float4 a, const float4 b) {
    bfv8 r;
    r[0]=f2bf(a.x); r[1]=f2bf(a.y); r[2]=f2bf(a.z); r[3]=f2bf(a.w);
    r[4]=f2bf(b.x); r[5]=f2bf(b.y); r[6]=f2bf(b.z); r[7]=f2bf(b.w);
    return r;
}
__device__ __forceinline__ void gload16(const void* g, void* l) {
    __builtin_amdgcn_global_load_lds(
        (const __attribute__((address_space(1))) unsigned int*)g,
        (__attribute__((address_space(3))) unsigned int*)l, 16, 0, 0);
}

// ---------------------------------------------------------------------------
__global__ __launch_bounds__(256) void convx(const float* __restrict__ src,
                                             short* __restrict__ dst, int n8)
{
    int i = blockIdx.x * blockDim.x + threadIdx.x;
    int stride = gridDim.x * blockDim.x;
    for (; i < n8; i += stride) {
        float4 a = ((const float4*)src)[2*i], b = ((const float4*)src)[2*i+1];
        ((bfv8*)dst)[i] = pack8(a, b);
    }
}

// ---------------------------------------------------------------------------
// transpose-convert: src f32 [R][C] -> dst bf16 [C][R]. Grid (C/64, R/64).
// ---------------------------------------------------------------------------
__global__ __launch_bounds__(256) void wtrans(const float* __restrict__ src,
                                              short* __restrict__ dst, int R, int C)
{
    __shared__ short tile[64][72];
    const int tid = threadIdx.x;
    const int r0 = blockIdx.y * 64, c0 = blockIdx.x * 64;
    {
        const int i = tid >> 2, c = (tid & 3) * 16;
        const float* sp = src + ((size_t)(r0 + i)) * C + c0 + c;
        float4 v0 = ((const float4*)sp)[0], v1 = ((const float4*)sp)[1];
        float4 v2 = ((const float4*)sp)[2], v3 = ((const float4*)sp)[3];
        *(bfv8*)&tile[i][c]     = pack8(v0, v1);
        *(bfv8*)&tile[i][c + 8] = pack8(v2, v3);
    }
    __syncthreads();
    {
        const int j = tid >> 2, rc = (tid & 3) * 16;
        bfv8 g0, g1;
#pragma unroll
        for (int jj = 0; jj < 8; ++jj) { g0[jj] = tile[rc + jj][j]; g1[jj] = tile[rc + 8 + jj][j]; }
        short* dp = dst + ((size_t)(c0 + j)) * R + r0 + rc;
        *(bfv8*)dp       = g0;
        *(bfv8*)(dp + 8) = g1;
    }
}

// ---------------------------------------------------------------------------
// 2-phase pipelined GEMM: C = A(MxK) * B^T(NxK layout), bf16 in, 128x128 tile,
// BK=32, 4 waves 2x2. Prefetch next K-step via global_load_lds before MFMA;
// one barrier per step (its drain lands after compute).
// ---------------------------------------------------------------------------
template<int OUT_MODE>
__global__ __launch_bounds__(256) void gemm_bf16(
    const short* __restrict__ A, int lda,
    const short* __restrict__ B, int ldb,
    void* __restrict__ Cptr, int ldc, int K)
{
    __shared__ short As[2][128 * 32];
    __shared__ short Bs[2][128 * 32];
    const int tid = threadIdx.x;
    const int w = tid >> 6, lane = tid & 63;
    const int lr = lane & 15, lg = lane >> 4;
    const int wr = w >> 1, wc = w & 1;
    const size_t bm = (size_t)blockIdx.y * 128, bn = (size_t)blockIdx.x * 128;

    f32x4 acc[4][4] = {};

    const int r0 = tid >> 2, ch = (tid & 3) * 8;
    const short* aB0 = A + (bm + r0) * (size_t)lda + ch;
    const short* aB1 = aB0 + 64 * (size_t)lda;
    const short* bB0 = B + (bn + r0) * (size_t)ldb + ch;
    const short* bB1 = bB0 + 64 * (size_t)ldb;
    const int wof = w * 512;

    // prologue: stage k0=0 into buf 0
    gload16(aB0, As[0] + wof);
    gload16(aB1, As[0] + wof + 2048);
    gload16(bB0, Bs[0] + wof);
    gload16(bB1, Bs[0] + wof + 2048);
    __syncthreads();

    int cur = 0;
    for (int k0 = 0; k0 < K; k0 += 32) {
        if (k0 + 32 < K) {   // prefetch next step into other buffer
            gload16(aB0 + k0 + 32, As[cur ^ 1] + wof);
            gload16(aB1 + k0 + 32, As[cur ^ 1] + wof + 2048);
            gload16(bB0 + k0 + 32, Bs[cur ^ 1] + wof);
            gload16(bB1 + k0 + 32, Bs[cur ^ 1] + wof + 2048);
        }
        bfv8 af[4], bfr[4];
#pragma unroll
        for (int i = 0; i < 4; ++i) {
            af[i]  = *(const bfv8*)&As[cur][(wr * 64 + i * 16 + lr) * 32 + lg * 8];
            bfr[i] = *(const bfv8*)&Bs[cur][(wc * 64 + i * 16 + lr) * 32 + lg * 8];
        }
#pragma unroll
        for (int i = 0; i < 4; ++i)
#pragma unroll
            for (int j = 0; j < 4; ++j)
                acc[i][j] = __builtin_amdgcn_mfma_f32_16x16x32_bf16(af[i], bfr[j], acc[i][j], 0, 0, 0);
        __syncthreads();
        cur ^= 1;
    }

    const size_t crow = bm + wr * 64 + 4 * lg;
    const size_t ccol = bn + wc * 64 + lr;
#pragma unroll
    for (int i = 0; i < 4; ++i)
#pragma unroll
        for (int j = 0; j < 4; ++j)
#pragma unroll
            for (int r = 0; r < 4; ++r) {
                size_t off = (crow + i * 16 + r) * (size_t)ldc + ccol + j * 16;
                if (OUT_MODE == 0) ((float*)Cptr)[off] = acc[i][j][r];
                else               ((short*)Cptr)[off] = f2bf(acc[i][j][r]);
            }
}

// ---------------------------------------------------------------------------
// k = rmsnorm(k_content + rope(k_pe)); bf16 in, bf16 head-major out [b,h,t,d]
// ---------------------------------------------------------------------------
__global__ __launch_bounds__(256) void finalize_k(
    const short* __restrict__ kc, const short* __restrict__ pe,
    const float* __restrict__ cosb, const float* __restrict__ sinb,
    short* __restrict__ kb)
{
    const int gw = blockIdx.x * 4 + (threadIdx.x >> 6);
    const int l = threadIdx.x & 63;
    const int r = gw >> 4, h = gw & 15;
    const int t = r & (TT - 1), b = r >> 11;
    const size_t kcb = (size_t)r * 4096 + h * 128;
    const size_t peb = (size_t)r * 2048 + h * 128;

    float x1 = bf2f(pe[peb + l]), x2 = bf2f(pe[peb + 64 + l]);
    float c = cosb[t * 64 + l], s = sinb[t * 64 + l];
    float lo = bf2f(kc[kcb + l])      + x1 * c + x2 * s;
    float hi = bf2f(kc[kcb + 64 + l]) - x1 * s + x2 * c;

    float ss = lo * lo + hi * hi;
#pragma unroll
    for (int o = 32; o; o >>= 1) ss += __shfl_xor(ss, o);
    float rr = rsqrtf(ss * (1.0f / 128.0f) + EPSV);
    const size_t ob = (((size_t)b * HH + h) * TT + t) * 128;
    kb[ob + l]      = f2bf(lo * rr);
    kb[ob + 64 + l] = f2bf(hi * rr);
}

// q = rmsnorm(q)*log2e/sqrt(D); bf16 row-major in, bf16 head-major out
__global__ __launch_bounds__(256) void finalize_q(
    const short* __restrict__ qi, short* __restrict__ qo)
{
    const int gw = blockIdx.x * 4 + (threadIdx.x >> 6);
    const int l = threadIdx.x & 63;
    const int r = gw >> 4, h = gw & 15;
    const int t = r & (TT - 1), b = r >> 11;
    const short* qp = qi + (size_t)r * 2048 + h * 128 + 2 * l;
    float a = bf2f(qp[0]), bq = bf2f(qp[1]);
    float ss = a * a + bq * bq;
#pragma unroll
    for (int o = 32; o; o >>= 1) ss += __shfl_xor(ss, o);
    float rr = rsqrtf(ss * (1.0f / 128.0f) + EPSV) * (QSCALE * LOG2E);
    short* op = qo + (((size_t)b * HH + h) * TT + t) * 128 + 2 * l;
    op[0] = f2bf(a * rr);
    op[1] = f2bf(bq * rr);
}

// v: KV2 cols 2048..4095 -> vb [b,h,d,t] bf16. Grid (T/64, 2, 32)
__global__ __launch_bounds__(256) void vtrans(
    const short* __restrict__ src, short* __restrict__ dst)
{
    __shared__ short tile[64][72];
    const int tt = blockIdx.x, dt = blockIdx.y, bh = blockIdx.z;
    const int tid = threadIdx.x;
    {
        const int i = tid >> 2, c = (tid & 3) * 16;
        const size_t sb = ((size_t)((bh >> 4) * TT + tt * 64 + i)) * 4096 + 2048 + (bh & 15) * 128 + dt * 64 + c;
        *(bfv8*)&tile[i][c]     = *(const bfv8*)&src[sb];
        *(bfv8*)&tile[i][c + 8] = *(const bfv8*)&src[sb + 8];
    }
    __syncthreads();
    {
        const int j = tid >> 2, rc = (tid & 3) * 16;
        bfv8 g0, g1;
#pragma unroll
        for (int jj = 0; jj < 8; ++jj) { g0[jj] = tile[rc + jj][j]; g1[jj] = tile[rc + 8 + jj][j]; }
        const size_t db = (((size_t)bh) * 128 + dt * 64 + j) * TT + tt * 64 + rc;
        *(bfv8*)&dst[db]     = g0;
        *(bfv8*)&dst[db + 8] = g1;
    }
}

// ---------------------------------------------------------------------------
// Flash attention tile step. Scores arrive in log2 domain (q pre-scaled).
// Defer-rescale (T13): skip o/l rescale while tile max stays within THRL of m.
// ---------------------------------------------------------------------------
__device__ __forceinline__ void attn_tile(
    const short* __restrict__ Ks, const short* __restrict__ Vs,
    short (&Psw)[16][72], const bfv8 aq[4], f32x4 o[8],
    float m[4], float l[4], int lr, int lg, int w, bool diag)
{
    f32x4 s[4];
#pragma unroll
    for (int ct = 0; ct < 4; ++ct) {
        f32x4 a = {0.f, 0.f, 0.f, 0.f};
        const int row = ct * 16 + lr;
#pragma unroll
        for (int ks = 0; ks < 4; ++ks) {
            const bfv8 bk = *(const bfv8*)&Ks[row * 128 + (((ks * 4 + lg) ^ (row & 7)) * 8)];
            a = __builtin_amdgcn_mfma_f32_16x16x32_bf16(aq[ks], bk, a, 0, 0, 0);
        }
        s[ct] = a;
    }
    if (diag) {
        const int rq = w * 16 + 4 * lg;
#pragma unroll
        for (int ct = 0; ct < 4; ++ct)
#pragma unroll
            for (int r = 0; r < 4; ++r)
                if (ct * 16 + lr > rq + r) s[ct][r] = -__builtin_inff();
    }
    float mt[4];
#pragma unroll
    for (int r = 0; r < 4; ++r) mt[r] = fmaxf(fmaxf(s[0][r], s[1][r]), fmaxf(s[2][r], s[3][r]));
#pragma unroll
    for (int off = 1; off < 16; off <<= 1)
#pragma unroll
        for (int r = 0; r < 4; ++r) mt[r] = fmaxf(mt[r], __shfl_xor(mt[r], off));

    float g = fmaxf(fmaxf(mt[0] - m[0], mt[1] - m[1]), fmaxf(mt[2] - m[2], mt[3] - m[3]));
    if (!__all(g <= THRL)) {
        float alpha[4];
#pragma unroll
        for (int r = 0; r < 4; ++r) {
            float mn = fmaxf(m[r], mt[r]);
            alpha[r] = exp2f(m[r] - mn);
            m[r] = mn;
            l[r] *= alpha[r];
        }
#pragma unroll
        for (int dt = 0; dt < 8; ++dt) {
            o[dt][0] *= alpha[0]; o[dt][1] *= alpha[1];
            o[dt][2] *= alpha[2]; o[dt][3] *= alpha[3];
        }
    }
#pragma unroll
    for (int ct = 0; ct < 4; ++ct)
#pragma unroll
        for (int r = 0; r < 4; ++r) s[ct][r] = exp2f(s[ct][r] - m[r]);
    float rs[4];
#pragma unroll
    for (int r = 0; r < 4; ++r) rs[r] = (s[0][r] + s[1][r]) + (s[2][r] + s[3][r]);
#pragma unroll
    for (int off = 1; off < 16; off <<= 1)
#pragma unroll
        for (int r = 0; r < 4; ++r) rs[r] += __shfl_xor(rs[r], off);
#pragma unroll
    for (int r = 0; r < 4; ++r) l[r] += rs[r];
#pragma unroll
    for (int ct = 0; ct < 4; ++ct)
#pragma unroll
        for (int r = 0; r < 4; ++r)
            Psw[4 * lg + r][ct * 16 + lr] = f2bf(s[ct][r]);
    const bfv8 pa0 = *(const bfv8*)&Psw[lr][lg * 8];
    const bfv8 pa1 = *(const bfv8*)&Psw[lr][32 + lg * 8];
#pragma unroll
    for (int dt = 0; dt < 8; ++dt) {
        const int row = dt * 16 + lr;
        const bfv8 bv0 = *(const bfv8*)&Vs[row * 64 + ((lg ^ (row & 7)) * 8)];
        const bfv8 bv1 = *(const bfv8*)&Vs[row * 64 + (((4 + lg) ^ (row & 7)) * 8)];
        o[dt] = __builtin_amdgcn_mfma_f32_16x16x32_bf16(pa0, bv0, o[dt], 0, 0, 0);
        o[dt] = __builtin_amdgcn_mfma_f32_16x16x32_bf16(pa1, bv1, o[dt], 0, 0, 0);
    }
}

// Pair-balanced causal flash attention, 2-phase pipelined K/V staging.
__global__ __launch_bounds__(256) void attn_kernel(
    const short* __restrict__ qg, const short* __restrict__ kg,
    const short* __restrict__ vg, short* __restrict__ y)
{
    __shared__ short Ks[2][64 * 128];
    __shared__ short Vs[2][128 * 64];
    __shared__ short Ps[4][16][72];

    const int pi = blockIdx.x, h = blockIdx.y, b = blockIdx.z;
    const int qt1 = pi, qt2 = 31 - pi;
    const int tid = threadIdx.x, w = tid >> 6, lane = tid & 63;
    const int lr = lane & 15, lg = lane >> 4;

    const size_t tok0 = ((size_t)b * HH + h) * TT;
    bfv8 aq1[4], aq2[4];
    {
        const size_t q1 = (tok0 + qt1 * 64 + w * 16 + lr) * 128;
        const size_t q2 = (tok0 + qt2 * 64 + w * 16 + lr) * 128;
#pragma unroll
        for (int ks = 0; ks < 4; ++ks) {
            aq1[ks] = *(const bfv8*)&qg[q1 + ks * 32 + lg * 8];
            aq2[ks] = *(const bfv8*)&qg[q2 + ks * 32 + lg * 8];
        }
    }
    f32x4 o1[8] = {}; f32x4 o2[8] = {};
    float m1[4], l1[4], m2[4], l2[4];
#pragma unroll
    for (int r = 0; r < 4; ++r) { m1[r] = m2[r] = -__builtin_inff(); l1[r] = l2[r] = 0.f; }

    const size_t vhead = ((size_t)b * HH + h) * (size_t)128 * TT;
    const int krow = tid >> 4, kub = tid & 15;
    const int vrow = tid >> 3, vub = tid & 7;
    const int wof = w * 512;

#define STAGE_KV(KT, BUF)                                                          \
    {                                                                              \
        const size_t kbase = (tok0 + (KT) * 64) * 128;                             \
        _Pragma("unroll")                                                          \
        for (int p = 0; p < 4; ++p) {                                              \
            int row = p * 16 + krow;                                               \
            int u = kub ^ (row & 7);                                               \
            gload16(kg + kbase + row * 128 + u * 8, Ks[BUF] + wof + p * 2048);     \
            int rv = p * 32 + vrow;                                                \
            int uv = vub ^ (rv & 7);                                               \
            gload16(vg + vhead + (size_t)rv * TT + (KT) * 64 + uv * 8,             \
                    Vs[BUF] + wof + p * 2048);                                     \
        }                                                                          \
    }

    STAGE_KV(0, 0);
    __syncthreads();

    int cur = 0;
    for (int kt = 0; kt <= qt2; ++kt) {
        if (kt < qt2) STAGE_KV(kt + 1, cur ^ 1);
        attn_tile(Ks[cur], Vs[cur], Ps[w], aq2, o2, m2, l2, lr, lg, w, kt == qt2);
        if (kt <= qt1)
            attn_tile(Ks[cur], Vs[cur], Ps[w], aq1, o1, m1, l1, lr, lg, w, kt == qt1);
        __syncthreads();
        cur ^= 1;
    }

#pragma unroll
    for (int r = 0; r < 4; ++r) {
        float inv1 = 1.0f / l1[r], inv2 = 1.0f / l2[r];
        const size_t y1 = ((size_t)b * TT + qt1 * 64 + w * 16 + 4 * lg + r) * 2048 + h * 128 + lr;
        const size_t y2 = ((size_t)b * TT + qt2 * 64 + w * 16 + 4 * lg + r) * 2048 + h * 128 + lr;
#pragma unroll
        for (int dt = 0; dt < 8; ++dt) {
            y[y1 + dt * 16] = f2bf(o1[dt][r] * inv1);
            y[y2 + dt * 16] = f2bf(o2[dt][r] * inv2);
        }
    }
}

// ---------------------------------------------------------------------------
extern "C" void kernel_launch(void* const* d_in, const int* in_sizes, int n_in,
                              void* d_out, int out_size, void* d_ws, size_t ws_size,
                              hipStream_t stream)
{
    const float* x      = (const float*)d_in[0];
    const float* cosb   = (const float*)d_in[1];
    const float* sinb   = (const float*)d_in[2];
    const float* wq_a   = (const float*)d_in[3];
    const float* wq_b   = (const float*)d_in[4];
    const float* wkv_a  = (const float*)d_in[5];
    const float* wk_b   = (const float*)d_in[6];
    const float* wkpe_b = (const float*)d_in[7];
    const float* wv_b   = (const float*)d_in[8];
    const float* wo     = (const float*)d_in[9];

    short* wsp = (short*)d_ws;
    short* W1  = wsp;                 // [2048][2048]  [wq_a^T ; wkv_a^T]
    short* W2  = wsp + 4194304;       // [4096][768]   [wk_b^T ; wv_b^T]
    short* W3  = wsp + 7340032;       // [2048][256]   wkpe_b^T
    short* W4  = wsp + 7864320;       // [2048][1024]  wq_b^T
    short* W5  = wsp + 9961472;       // [2048][2048]  wo^T
    short* C1  = wsp + 14155776;      // [4096][2048]  qlat|kvlat; later y
    short* KV2 = wsp + 22544384;      // [4096][4096]  k_content|v; later qb
    short* KPE = wsp + 39321600;      // [4096][2048]  k_pe; later qbuf
    short* KB  = wsp + 47710208;      // [b,h,t,d]
    short* VB  = wsp + 56098816;      // [b,h,d,t]
    short* XB  = (short*)d_out;       // x as bf16 (d_out reused as scratch)

    dim3 blk(256);

    convx<<<2048, blk, 0, stream>>>(x, XB, 1048576);
    wtrans<<<dim3(16, 32), blk, 0, stream>>>(wq_a,   W1,                2048, 1024);
    wtrans<<<dim3(16, 32), blk, 0, stream>>>(wkv_a,  W1 + 1024 * 2048,  2048, 1024);
    wtrans<<<dim3(32, 12), blk, 0, stream>>>(wk_b,   W2,                 768, 2048);
    wtrans<<<dim3(32, 12), blk, 0, stream>>>(wv_b,   W2 + 2048 * 768,    768, 2048);
    wtrans<<<dim3(32,  4), blk, 0, stream>>>(wkpe_b, W3,                 256, 2048);
    wtrans<<<dim3(32, 16), blk, 0, stream>>>(wq_b,   W4,                1024, 2048);
    wtrans<<<dim3(32, 32), blk, 0, stream>>>(wo,     W5,                2048, 2048);

    // [qlat|kvlat] = x @ [wq_a|wkv_a]
    gemm_bf16<1><<<dim3(16, 32), blk, 0, stream>>>(XB, 2048, W1, 2048, C1, 2048, 2048);
    // [k_content|v] = kv_content @ [wk_b|wv_b]
    gemm_bf16<1><<<dim3(32, 32), blk, 0, stream>>>(C1 + 1280, 2048, W2, 768, KV2, 4096, 768);
    // k_pe = kv_pe @ wkpe_b
    gemm_bf16<1><<<dim3(16, 32), blk, 0, stream>>>(C1 + 1024, 2048, W3, 256, KPE, 2048, 256);

    finalize_k<<<16384, blk, 0, stream>>>(KV2, KPE, cosb, sinb, KB);
    vtrans<<<dim3(32, 2, 32), blk, 0, stream>>>(KV2, VB);

    // qbuf = qlat @ wq_b  (into KPE slot)
    gemm_bf16<1><<<dim3(16, 32), blk, 0, stream>>>(C1, 2048, W4, 1024, KPE, 2048, 1024);
    finalize_q<<<16384, blk, 0, stream>>>(KPE, KV2);   // qb into KV2 slot

    // attention: y into C1 slot
    attn_kernel<<<dim3(16, 16, 2), blk, 0, stream>>>(KV2, KB, VB, C1);

    // out = y @ wo
    gemm_bf16<0><<<dim3(16, 32), blk, 0, stream>>>(C1, 2048, W5, 2048, d_out, 2048, 2048);
}

// Round 4
// 357.116 us; speedup vs baseline: 2.9975x; 1.0499x over previous
//
#include <hip/hip_runtime.h>
#include <cstddef>
#include <cstdint>

#define TT 2048
#define HH 16
#define EPSV 1.1920929e-07f
#define QSCALE 0.08838834764831845f   // 1/sqrt(128)
#define LOG2E 1.4426950408889634f
#define THRL 11.0f                    // defer-rescale threshold (log2 units)

typedef short bfv8 __attribute__((ext_vector_type(8)));
typedef float f32x4 __attribute__((ext_vector_type(4)));

__device__ __forceinline__ short f2bf(float f) {
    unsigned u = __builtin_bit_cast(unsigned, f);
    u += 0x7FFFu + ((u >> 16) & 1u);          // RNE
    return (short)(u >> 16);
}
__device__ __forceinline__ float bf2f(short s) {
    unsigned u = ((unsigned)(unsigned short)s) << 16;
    return __builtin_bit_cast(float, u);
}
__device__ __forceinline__ bfv8 pack8(const float4 a, const float4 b) {
    bfv8 r;
    r[0]=f2bf(a.x); r[1]=f2bf(a.y); r[2]=f2bf(a.z); r[3]=f2bf(a.w);
    r[4]=f2bf(b.x); r[5]=f2bf(b.y); r[6]=f2bf(b.z); r[7]=f2bf(b.w);
    return r;
}
__device__ __forceinline__ void gload16(const void* g, void* l) {
    __builtin_amdgcn_global_load_lds(
        (const __attribute__((address_space(1))) unsigned int*)g,
        (__attribute__((address_space(3))) unsigned int*)l, 16, 0, 0);
}

// ---------------------------------------------------------------------------
__global__ __launch_bounds__(256) void convx(const float* __restrict__ src,
                                             short* __restrict__ dst, int n8)
{
    int i = blockIdx.x * blockDim.x + threadIdx.x;
    int stride = gridDim.x * blockDim.x;
    for (; i < n8; i += stride) {
        float4 a = ((const float4*)src)[2*i], b = ((const float4*)src)[2*i+1];
        ((bfv8*)dst)[i] = pack8(a, b);
    }
}

// ---------------------------------------------------------------------------
// transpose-convert: src f32 [R][C] -> dst bf16 [C][R]. Grid (C/64, R/64).
// ---------------------------------------------------------------------------
__global__ __launch_bounds__(256) void wtrans(const float* __restrict__ src,
                                              short* __restrict__ dst, int R, int C)
{
    __shared__ short tile[64][72];
    const int tid = threadIdx.x;
    const int r0 = blockIdx.y * 64, c0 = blockIdx.x * 64;
    {
        const int i = tid >> 2, c = (tid & 3) * 16;
        const float* sp = src + ((size_t)(r0 + i)) * C + c0 + c;
        float4 v0 = ((const float4*)sp)[0], v1 = ((const float4*)sp)[1];
        float4 v2 = ((const float4*)sp)[2], v3 = ((const float4*)sp)[3];
        *(bfv8*)&tile[i][c]     = pack8(v0, v1);
        *(bfv8*)&tile[i][c + 8] = pack8(v2, v3);
    }
    __syncthreads();
    {
        const int j = tid >> 2, rc = (tid & 3) * 16;
        bfv8 g0, g1;
#pragma unroll
        for (int jj = 0; jj < 8; ++jj) { g0[jj] = tile[rc + jj][j]; g1[jj] = tile[rc + 8 + jj][j]; }
        short* dp = dst + ((size_t)(c0 + j)) * R + r0 + rc;
        *(bfv8*)dp       = g0;
        *(bfv8*)(dp + 8) = g1;
    }
}

// ---------------------------------------------------------------------------
// 2-phase pipelined GEMM: C = A(MxK) * B^T(NxK layout), bf16 in, 128x128 tile.
// ---------------------------------------------------------------------------
template<int OUT_MODE>
__global__ __launch_bounds__(256) void gemm_bf16(
    const short* __restrict__ A, int lda,
    const short* __restrict__ B, int ldb,
    void* __restrict__ Cptr, int ldc, int K)
{
    __shared__ short As[2][128 * 32];
    __shared__ short Bs[2][128 * 32];
    const int tid = threadIdx.x;
    const int w = tid >> 6, lane = tid & 63;
    const int lr = lane & 15, lg = lane >> 4;
    const int wr = w >> 1, wc = w & 1;
    const size_t bm = (size_t)blockIdx.y * 128, bn = (size_t)blockIdx.x * 128;

    f32x4 acc[4][4] = {};

    const int r0 = tid >> 2, ch = (tid & 3) * 8;
    const short* aB0 = A + (bm + r0) * (size_t)lda + ch;
    const short* aB1 = aB0 + 64 * (size_t)lda;
    const short* bB0 = B + (bn + r0) * (size_t)ldb + ch;
    const short* bB1 = bB0 + 64 * (size_t)ldb;
    const int wof = w * 512;

    gload16(aB0, As[0] + wof);
    gload16(aB1, As[0] + wof + 2048);
    gload16(bB0, Bs[0] + wof);
    gload16(bB1, Bs[0] + wof + 2048);
    __syncthreads();

    int cur = 0;
    for (int k0 = 0; k0 < K; k0 += 32) {
        if (k0 + 32 < K) {
            gload16(aB0 + k0 + 32, As[cur ^ 1] + wof);
            gload16(aB1 + k0 + 32, As[cur ^ 1] + wof + 2048);
            gload16(bB0 + k0 + 32, Bs[cur ^ 1] + wof);
            gload16(bB1 + k0 + 32, Bs[cur ^ 1] + wof + 2048);
        }
        bfv8 af[4], bfr[4];
#pragma unroll
        for (int i = 0; i < 4; ++i) {
            af[i]  = *(const bfv8*)&As[cur][(wr * 64 + i * 16 + lr) * 32 + lg * 8];
            bfr[i] = *(const bfv8*)&Bs[cur][(wc * 64 + i * 16 + lr) * 32 + lg * 8];
        }
#pragma unroll
        for (int i = 0; i < 4; ++i)
#pragma unroll
            for (int j = 0; j < 4; ++j)
                acc[i][j] = __builtin_amdgcn_mfma_f32_16x16x32_bf16(af[i], bfr[j], acc[i][j], 0, 0, 0);
        __syncthreads();
        cur ^= 1;
    }

    const size_t crow = bm + wr * 64 + 4 * lg;
    const size_t ccol = bn + wc * 64 + lr;
#pragma unroll
    for (int i = 0; i < 4; ++i)
#pragma unroll
        for (int j = 0; j < 4; ++j)
#pragma unroll
            for (int r = 0; r < 4; ++r) {
                size_t off = (crow + i * 16 + r) * (size_t)ldc + ccol + j * 16;
                if (OUT_MODE == 0) ((float*)Cptr)[off] = acc[i][j][r];
                else               ((short*)Cptr)[off] = f2bf(acc[i][j][r]);
            }
}

// ---------------------------------------------------------------------------
// k = rmsnorm(k_content + rope(k_pe)); bf16 in, bf16 head-major out [b,h,t,d]
// ---------------------------------------------------------------------------
__global__ __launch_bounds__(256) void finalize_k(
    const short* __restrict__ kc, const short* __restrict__ pe,
    const float* __restrict__ cosb, const float* __restrict__ sinb,
    short* __restrict__ kb)
{
    const int gw = blockIdx.x * 4 + (threadIdx.x >> 6);
    const int l = threadIdx.x & 63;
    const int r = gw >> 4, h = gw & 15;
    const int t = r & (TT - 1), b = r >> 11;
    const size_t kcb = (size_t)r * 4096 + h * 128;
    const size_t peb = (size_t)r * 2048 + h * 128;

    float x1 = bf2f(pe[peb + l]), x2 = bf2f(pe[peb + 64 + l]);
    float c = cosb[t * 64 + l], s = sinb[t * 64 + l];
    float lo = bf2f(kc[kcb + l])      + x1 * c + x2 * s;
    float hi = bf2f(kc[kcb + 64 + l]) - x1 * s + x2 * c;

    float ss = lo * lo + hi * hi;
#pragma unroll
    for (int o = 32; o; o >>= 1) ss += __shfl_xor(ss, o);
    float rr = rsqrtf(ss * (1.0f / 128.0f) + EPSV);
    const size_t ob = (((size_t)b * HH + h) * TT + t) * 128;
    kb[ob + l]      = f2bf(lo * rr);
    kb[ob + 64 + l] = f2bf(hi * rr);
}

// q = rmsnorm(q)*log2e/sqrt(D); bf16 row-major in, bf16 head-major out
__global__ __launch_bounds__(256) void finalize_q(
    const short* __restrict__ qi, short* __restrict__ qo)
{
    const int gw = blockIdx.x * 4 + (threadIdx.x >> 6);
    const int l = threadIdx.x & 63;
    const int r = gw >> 4, h = gw & 15;
    const int t = r & (TT - 1), b = r >> 11;
    const short* qp = qi + (size_t)r * 2048 + h * 128 + 2 * l;
    float a = bf2f(qp[0]), bq = bf2f(qp[1]);
    float ss = a * a + bq * bq;
#pragma unroll
    for (int o = 32; o; o >>= 1) ss += __shfl_xor(ss, o);
    float rr = rsqrtf(ss * (1.0f / 128.0f) + EPSV) * (QSCALE * LOG2E);
    short* op = qo + (((size_t)b * HH + h) * TT + t) * 128 + 2 * l;
    op[0] = f2bf(a * rr);
    op[1] = f2bf(bq * rr);
}

// v: KV2 cols 2048..4095 -> vb [b,h,d,t] bf16. Grid (T/64, 2, 32)
__global__ __launch_bounds__(256) void vtrans(
    const short* __restrict__ src, short* __restrict__ dst)
{
    __shared__ short tile[64][72];
    const int tt = blockIdx.x, dt = blockIdx.y, bh = blockIdx.z;
    const int tid = threadIdx.x;
    {
        const int i = tid >> 2, c = (tid & 3) * 16;
        const size_t sb = ((size_t)((bh >> 4) * TT + tt * 64 + i)) * 4096 + 2048 + (bh & 15) * 128 + dt * 64 + c;
        *(bfv8*)&tile[i][c]     = *(const bfv8*)&src[sb];
        *(bfv8*)&tile[i][c + 8] = *(const bfv8*)&src[sb + 8];
    }
    __syncthreads();
    {
        const int j = tid >> 2, rc = (tid & 3) * 16;
        bfv8 g0, g1;
#pragma unroll
        for (int jj = 0; jj < 8; ++jj) { g0[jj] = tile[rc + jj][j]; g1[jj] = tile[rc + 8 + jj][j]; }
        const size_t db = (((size_t)bh) * 128 + dt * 64 + j) * TT + tt * 64 + rc;
        *(bfv8*)&dst[db]     = g0;
        *(bfv8*)&dst[db + 8] = g1;
    }
}

// ---------------------------------------------------------------------------
// attn helpers
// ---------------------------------------------------------------------------
__device__ __forceinline__ void qk_tile(const short* __restrict__ Ks,
    const bfv8 aq[4], f32x4 s[4], int lr, int lg)
{
#pragma unroll
    for (int ct = 0; ct < 4; ++ct) {
        f32x4 a = {0.f, 0.f, 0.f, 0.f};
        const int row = ct * 16 + lr;
#pragma unroll
        for (int ks = 0; ks < 4; ++ks) {
            const bfv8 bk = *(const bfv8*)&Ks[row * 128 + (((ks * 4 + lg) ^ (row & 7)) * 8)];
            a = __builtin_amdgcn_mfma_f32_16x16x32_bf16(aq[ks], bk, a, 0, 0, 0);
        }
        s[ct] = a;
    }
}

__device__ __forceinline__ void mask_diag(f32x4 s[4], int lr, int lg, int w)
{
    const int rq = w * 16 + 4 * lg;
#pragma unroll
    for (int ct = 0; ct < 4; ++ct)
#pragma unroll
        for (int r = 0; r < 4; ++r)
            if (ct * 16 + lr > rq + r) s[ct][r] = -__builtin_inff();
}

// softmax for one stream (used in single-stream segment)
__device__ __forceinline__ void softmax1(f32x4 s[4], float m[4], float l[4], f32x4 o[8])
{
    float mt[4];
#pragma unroll
    for (int r = 0; r < 4; ++r) mt[r] = fmaxf(fmaxf(s[0][r], s[1][r]), fmaxf(s[2][r], s[3][r]));
#pragma unroll
    for (int off = 1; off < 16; off <<= 1)
#pragma unroll
        for (int r = 0; r < 4; ++r) mt[r] = fmaxf(mt[r], __shfl_xor(mt[r], off));
    float g = fmaxf(fmaxf(mt[0] - m[0], mt[1] - m[1]), fmaxf(mt[2] - m[2], mt[3] - m[3]));
    if (!__all(g <= THRL)) {
        float alpha[4];
#pragma unroll
        for (int r = 0; r < 4; ++r) {
            float mn = fmaxf(m[r], mt[r]);
            alpha[r] = exp2f(m[r] - mn);
            m[r] = mn; l[r] *= alpha[r];
        }
#pragma unroll
        for (int dt = 0; dt < 8; ++dt) {
            o[dt][0] *= alpha[0]; o[dt][1] *= alpha[1];
            o[dt][2] *= alpha[2]; o[dt][3] *= alpha[3];
        }
    }
#pragma unroll
    for (int ct = 0; ct < 4; ++ct)
#pragma unroll
        for (int r = 0; r < 4; ++r) s[ct][r] = exp2f(s[ct][r] - m[r]);
    float rs[4];
#pragma unroll
    for (int r = 0; r < 4; ++r) rs[r] = (s[0][r] + s[1][r]) + (s[2][r] + s[3][r]);
#pragma unroll
    for (int off = 1; off < 16; off <<= 1)
#pragma unroll
        for (int r = 0; r < 4; ++r) rs[r] += __shfl_xor(rs[r], off);
#pragma unroll
    for (int r = 0; r < 4; ++r) l[r] += rs[r];
}

// softmax for both streams, reduce rounds interleaved (independent chains)
__device__ __forceinline__ void softmax2(
    f32x4 s1[4], f32x4 s2[4],
    float m1[4], float l1[4], float m2[4], float l2[4],
    f32x4 o1[8], f32x4 o2[8])
{
    float mt1[4], mt2[4];
#pragma unroll
    for (int r = 0; r < 4; ++r) {
        mt1[r] = fmaxf(fmaxf(s1[0][r], s1[1][r]), fmaxf(s1[2][r], s1[3][r]));
        mt2[r] = fmaxf(fmaxf(s2[0][r], s2[1][r]), fmaxf(s2[2][r], s2[3][r]));
    }
#pragma unroll
    for (int off = 1; off < 16; off <<= 1)
#pragma unroll
        for (int r = 0; r < 4; ++r) {
            mt1[r] = fmaxf(mt1[r], __shfl_xor(mt1[r], off));
            mt2[r] = fmaxf(mt2[r], __shfl_xor(mt2[r], off));
        }
    float g1 = fmaxf(fmaxf(mt1[0] - m1[0], mt1[1] - m1[1]), fmaxf(mt1[2] - m1[2], mt1[3] - m1[3]));
    float g2 = fmaxf(fmaxf(mt2[0] - m2[0], mt2[1] - m2[1]), fmaxf(mt2[2] - m2[2], mt2[3] - m2[3]));
    if (!__all(g1 <= THRL)) {
        float alpha[4];
#pragma unroll
        for (int r = 0; r < 4; ++r) {
            float mn = fmaxf(m1[r], mt1[r]);
            alpha[r] = exp2f(m1[r] - mn);
            m1[r] = mn; l1[r] *= alpha[r];
        }
#pragma unroll
        for (int dt = 0; dt < 8; ++dt) {
            o1[dt][0] *= alpha[0]; o1[dt][1] *= alpha[1];
            o1[dt][2] *= alpha[2]; o1[dt][3] *= alpha[3];
        }
    }
    if (!__all(g2 <= THRL)) {
        float alpha[4];
#pragma unroll
        for (int r = 0; r < 4; ++r) {
            float mn = fmaxf(m2[r], mt2[r]);
            alpha[r] = exp2f(m2[r] - mn);
            m2[r] = mn; l2[r] *= alpha[r];
        }
#pragma unroll
        for (int dt = 0; dt < 8; ++dt) {
            o2[dt][0] *= alpha[0]; o2[dt][1] *= alpha[1];
            o2[dt][2] *= alpha[2]; o2[dt][3] *= alpha[3];
        }
    }
#pragma unroll
    for (int ct = 0; ct < 4; ++ct)
#pragma unroll
        for (int r = 0; r < 4; ++r) {
            s1[ct][r] = exp2f(s1[ct][r] - m1[r]);
            s2[ct][r] = exp2f(s2[ct][r] - m2[r]);
        }
    float rs1[4], rs2[4];
#pragma unroll
    for (int r = 0; r < 4; ++r) {
        rs1[r] = (s1[0][r] + s1[1][r]) + (s1[2][r] + s1[3][r]);
        rs2[r] = (s2[0][r] + s2[1][r]) + (s2[2][r] + s2[3][r]);
    }
#pragma unroll
    for (int off = 1; off < 16; off <<= 1)
#pragma unroll
        for (int r = 0; r < 4; ++r) {
            rs1[r] += __shfl_xor(rs1[r], off);
            rs2[r] += __shfl_xor(rs2[r], off);
        }
#pragma unroll
    for (int r = 0; r < 4; ++r) { l1[r] += rs1[r]; l2[r] += rs2[r]; }
}

__device__ __forceinline__ void pv_tile(const short* __restrict__ Vs,
    short (&Psw)[16][72], const f32x4 s[4], f32x4 o[8], int lr, int lg)
{
#pragma unroll
    for (int ct = 0; ct < 4; ++ct)
#pragma unroll
        for (int r = 0; r < 4; ++r)
            Psw[4 * lg + r][ct * 16 + lr] = f2bf(s[ct][r]);
    const bfv8 pa0 = *(const bfv8*)&Psw[lr][lg * 8];
    const bfv8 pa1 = *(const bfv8*)&Psw[lr][32 + lg * 8];
#pragma unroll
    for (int dt = 0; dt < 8; ++dt) {
        const int row = dt * 16 + lr;
        const bfv8 bv0 = *(const bfv8*)&Vs[row * 64 + ((lg ^ (row & 7)) * 8)];
        const bfv8 bv1 = *(const bfv8*)&Vs[row * 64 + (((4 + lg) ^ (row & 7)) * 8)];
        o[dt] = __builtin_amdgcn_mfma_f32_16x16x32_bf16(pa0, bv0, o[dt], 0, 0, 0);
        o[dt] = __builtin_amdgcn_mfma_f32_16x16x32_bf16(pa1, bv1, o[dt], 0, 0, 0);
    }
}

// ---------------------------------------------------------------------------
// Pair-balanced causal flash attention, dual-stream interleaved, 2-phase
// pipelined K/V staging, XCD-clustered work remap.
// ---------------------------------------------------------------------------
__global__ __launch_bounds__(256) void attn_kernel(
    const short* __restrict__ qg, const short* __restrict__ kg,
    const short* __restrict__ vg, short* __restrict__ y)
{
    __shared__ short Ks[2][64 * 128];
    __shared__ short Vs[2][128 * 64];
    __shared__ short Ps[4][16][72];

    // XCD-clustered remap: same-(b,h) pair-blocks land on one XCD
    const int lin = blockIdx.x + 16 * blockIdx.y + 256 * blockIdx.z;
    const int work = (lin & 7) * 64 + (lin >> 3);
    const int pi = work & 15, h = (work >> 4) & 15, b = work >> 8;
    const int qt1 = pi, qt2 = 31 - pi;
    const int tid = threadIdx.x, w = tid >> 6, lane = tid & 63;
    const int lr = lane & 15, lg = lane >> 4;

    const size_t tok0 = ((size_t)b * HH + h) * TT;
    bfv8 aq1[4], aq2[4];
    {
        const size_t q1 = (tok0 + qt1 * 64 + w * 16 + lr) * 128;
        const size_t q2 = (tok0 + qt2 * 64 + w * 16 + lr) * 128;
#pragma unroll
        for (int ks = 0; ks < 4; ++ks) {
            aq1[ks] = *(const bfv8*)&qg[q1 + ks * 32 + lg * 8];
            aq2[ks] = *(const bfv8*)&qg[q2 + ks * 32 + lg * 8];
        }
    }
    f32x4 o1[8] = {}; f32x4 o2[8] = {};
    float m1[4], l1[4], m2[4], l2[4];
#pragma unroll
    for (int r = 0; r < 4; ++r) { m1[r] = m2[r] = -__builtin_inff(); l1[r] = l2[r] = 0.f; }

    const size_t vhead = ((size_t)b * HH + h) * (size_t)128 * TT;
    const int krow = tid >> 4, kub = tid & 15;
    const int vrow = tid >> 3, vub = tid & 7;
    const int wof = w * 512;

#define STAGE_KV(KT, BUF)                                                          \
    {                                                                              \
        const size_t kbase = (tok0 + (KT) * 64) * 128;                             \
        _Pragma("unroll")                                                          \
        for (int p = 0; p < 4; ++p) {                                              \
            int row = p * 16 + krow;                                               \
            int u = kub ^ (row & 7);                                               \
            gload16(kg + kbase + row * 128 + u * 8, Ks[BUF] + wof + p * 2048);     \
            int rv = p * 32 + vrow;                                                \
            int uv = vub ^ (rv & 7);                                               \
            gload16(vg + vhead + (size_t)rv * TT + (KT) * 64 + uv * 8,             \
                    Vs[BUF] + wof + p * 2048);                                     \
        }                                                                          \
    }

    STAGE_KV(0, 0);
    __syncthreads();

    int cur = 0;
    // segment 1: both streams (kt = 0..qt1; qt1 < qt2 always)
    for (int kt = 0; kt <= qt1; ++kt) {
        if (kt < qt2) STAGE_KV(kt + 1, cur ^ 1);
        f32x4 s1[4], s2[4];
        qk_tile(Ks[cur], aq2, s2, lr, lg);
        qk_tile(Ks[cur], aq1, s1, lr, lg);
        if (kt == qt1) mask_diag(s1, lr, lg, w);
        softmax2(s1, s2, m1, l1, m2, l2, o1, o2);
        pv_tile(Vs[cur], Ps[w], s2, o2, lr, lg);
        pv_tile(Vs[cur], Ps[w], s1, o1, lr, lg);
        __syncthreads();
        cur ^= 1;
    }
    // segment 2: stream2 only (kt = qt1+1..qt2)
    for (int kt = qt1 + 1; kt <= qt2; ++kt) {
        if (kt < qt2) STAGE_KV(kt + 1, cur ^ 1);
        f32x4 s2[4];
        qk_tile(Ks[cur], aq2, s2, lr, lg);
        if (kt == qt2) mask_diag(s2, lr, lg, w);
        softmax1(s2, m2, l2, o2);
        pv_tile(Vs[cur], Ps[w], s2, o2, lr, lg);
        __syncthreads();
        cur ^= 1;
    }

#pragma unroll
    for (int r = 0; r < 4; ++r) {
        float inv1 = 1.0f / l1[r], inv2 = 1.0f / l2[r];
        const size_t y1 = ((size_t)b * TT + qt1 * 64 + w * 16 + 4 * lg + r) * 2048 + h * 128 + lr;
        const size_t y2 = ((size_t)b * TT + qt2 * 64 + w * 16 + 4 * lg + r) * 2048 + h * 128 + lr;
#pragma unroll
        for (int dt = 0; dt < 8; ++dt) {
            y[y1 + dt * 16] = f2bf(o1[dt][r] * inv1);
            y[y2 + dt * 16] = f2bf(o2[dt][r] * inv2);
        }
    }
}

// ---------------------------------------------------------------------------
extern "C" void kernel_launch(void* const* d_in, const int* in_sizes, int n_in,
                              void* d_out, int out_size, void* d_ws, size_t ws_size,
                              hipStream_t stream)
{
    const float* x      = (const float*)d_in[0];
    const float* cosb   = (const float*)d_in[1];
    const float* sinb   = (const float*)d_in[2];
    const float* wq_a   = (const float*)d_in[3];
    const float* wq_b   = (const float*)d_in[4];
    const float* wkv_a  = (const float*)d_in[5];
    const float* wk_b   = (const float*)d_in[6];
    const float* wkpe_b = (const float*)d_in[7];
    const float* wv_b   = (const float*)d_in[8];
    const float* wo     = (const float*)d_in[9];

    short* wsp = (short*)d_ws;
    short* W1  = wsp;                 // [2048][2048]  [wq_a^T ; wkv_a^T]
    short* W2  = wsp + 4194304;       // [4096][768]   [wk_b^T ; wv_b^T]
    short* W3  = wsp + 7340032;       // [2048][256]   wkpe_b^T
    short* W4  = wsp + 7864320;       // [2048][1024]  wq_b^T
    short* W5  = wsp + 9961472;       // [2048][2048]  wo^T
    short* C1  = wsp + 14155776;      // [4096][2048]  qlat|kvlat; later y
    short* KV2 = wsp + 22544384;      // [4096][4096]  k_content|v; later qb
    short* KPE = wsp + 39321600;      // [4096][2048]  k_pe; later qbuf
    short* KB  = wsp + 47710208;      // [b,h,t,d]
    short* VB  = wsp + 56098816;      // [b,h,d,t]
    short* XB  = (short*)d_out;       // x as bf16 (d_out reused as scratch)

    dim3 blk(256);

    convx<<<2048, blk, 0, stream>>>(x, XB, 1048576);
    wtrans<<<dim3(16, 32), blk, 0, stream>>>(wq_a,   W1,                2048, 1024);
    wtrans<<<dim3(16, 32), blk, 0, stream>>>(wkv_a,  W1 + 1024 * 2048,  2048, 1024);
    wtrans<<<dim3(32, 12), blk, 0, stream>>>(wk_b,   W2,                 768, 2048);
    wtrans<<<dim3(32, 12), blk, 0, stream>>>(wv_b,   W2 + 2048 * 768,    768, 2048);
    wtrans<<<dim3(32,  4), blk, 0, stream>>>(wkpe_b, W3,                 256, 2048);
    wtrans<<<dim3(32, 16), blk, 0, stream>>>(wq_b,   W4,                1024, 2048);
    wtrans<<<dim3(32, 32), blk, 0, stream>>>(wo,     W5,                2048, 2048);

    // [qlat|kvlat] = x @ [wq_a|wkv_a]
    gemm_bf16<1><<<dim3(16, 32), blk, 0, stream>>>(XB, 2048, W1, 2048, C1, 2048, 2048);
    // [k_content|v] = kv_content @ [wk_b|wv_b]
    gemm_bf16<1><<<dim3(32, 32), blk, 0, stream>>>(C1 + 1280, 2048, W2, 768, KV2, 4096, 768);
    // k_pe = kv_pe @ wkpe_b
    gemm_bf16<1><<<dim3(16, 32), blk, 0, stream>>>(C1 + 1024, 2048, W3, 256, KPE, 2048, 256);

    finalize_k<<<16384, blk, 0, stream>>>(KV2, KPE, cosb, sinb, KB);
    vtrans<<<dim3(32, 2, 32), blk, 0, stream>>>(KV2, VB);

    // qbuf = qlat @ wq_b  (into KPE slot)
    gemm_bf16<1><<<dim3(16, 32), blk, 0, stream>>>(C1, 2048, W4, 1024, KPE, 2048, 1024);
    finalize_q<<<16384, blk, 0, stream>>>(KPE, KV2);   // qb into KV2 slot

    // attention: y into C1 slot
    attn_kernel<<<dim3(16, 16, 2), blk, 0, stream>>>(KV2, KB, VB, C1);

    // out = y @ wo
    gemm_bf16<0><<<dim3(16, 32), blk, 0, stream>>>(C1, 2048, W5, 2048, d_out, 2048, 2048);
}